// Round 9
// baseline (203.926 us; speedup 1.0000x reference)
//
#include <hip/hip_runtime.h>
#include <math.h>

// PHM adapter: down (768->192, n=4 rank-1 kron) -> gelu_new -> up (192->768).
// Round 13 (= round-12 resubmit, simplified CFG; r12 bench was an opaque
// container failure -- infra telemetry shows 760-1020s pushes on recent
// successful rounds, failures track infra health not source content).
// 3-SLOT LOAD RING (MLP attack). Rounds 0/9/11 all hit 63-65us with
// different structures; permlane (r11) removed all mid-chain DS stalls and
// changed nothing -> not pipe-bound. Model: each wave keeps only 6KB (1
// pair) of loads in flight, computes ~1.2K cyc, then waits ~35K cyc for its
// next 12KB at the wave's share of delivered BW. The r2 spill run proved
// 3.6 TB/s deliverable to this pattern (vs our 2.35) when many more
// requests are outstanding -> raise per-wave MLP. Prologue issues loads for
// 3 pairs back-to-back (18KB in flight); each compute step re-issues its
// freed slot 3 strides ahead (wave-uniform guard -> no wasted DRAM reads).
// To fit <=128 VGPR with 72 data regs, ALL persistent weight regs (bd, rdw,
// bu = 27 floats) demoted to LDS (DS pipe is idle post-permlane; r7 proved
// DS ops don't move the needle). Keeps: coalesced remap p=a*192+4*(r+16u)+j,
// permlane broadcast, nt stores, no min-wave hint ((256,4) pins VGPR=64 and
// spills wholesale -- r2).

#define SQ2PI 0.79788456080286535588f

typedef float vfloat4 __attribute__((ext_vector_type(4)));
typedef unsigned int vuint2 __attribute__((ext_vector_type(2)));

template<int CTRL>
__device__ __forceinline__ float ror_add(float v) {
    // v + rotate_within_16(v, CTRL)  (DPP row_ror — VALU pipe, no DS traffic)
    int s = __builtin_amdgcn_update_dpp(0, __float_as_int(v), CTRL, 0xF, 0xF, true);
    return v + __int_as_float(s);
}
__device__ __forceinline__ float reduce16(float v) {
    v = ror_add<0x121>(v);   // row_ror:1
    v = ror_add<0x122>(v);   // row_ror:2
    v = ror_add<0x124>(v);   // row_ror:4
    v = ror_add<0x128>(v);   // row_ror:8
    return v;                // every lane: sum over its 16-lane row
}

// v_permlane16_swap_b32: exchanges odd 16-lane rows of d with even rows of s.
// v_permlane32_swap_b32: exchanges rows {2,3} of d with rows {0,1} of s.
__device__ __forceinline__ void swap16(float& d, float& s) {
    vuint2 t = __builtin_amdgcn_permlane16_swap(__float_as_uint(d), __float_as_uint(s), false, false);
    d = __uint_as_float(t.x);  s = __uint_as_float(t.y);
}
__device__ __forceinline__ void swap32(float& d, float& s) {
    vuint2 t = __builtin_amdgcn_permlane32_swap(__float_as_uint(d), __float_as_uint(s), false, false);
    d = __uint_as_float(t.x);  s = __uint_as_float(t.y);
}
// After reduce16, all lanes of row a hold H_a. Broadcast all four H's to
// every lane in 3 swap instructions (VALU pipe), no cndmask needed.
__device__ __forceinline__ void bcast4(float h, float& b0, float& b1, float& b2, float& b3) {
    float y1 = h, y2 = h;
    swap16(y1, y2);                     // y1 = H[a&2], y2 = H[(a&2)|1]
    b0 = y1; b2 = y1; swap32(b0, b2);   // b0 = H0, b2 = H2 (broadcast)
    b1 = y2; b3 = y2; swap32(b1, b3);   // b1 = H1, b3 = H3 (broadcast)
}

__device__ __forceinline__ void nt_store4(float* p, const float4& v) {
    vfloat4 nv;
    nv.x = v.x; nv.y = v.y; nv.z = v.z; nv.w = v.w;
    __builtin_nontemporal_store(nv, (vfloat4*)p);
}

struct Slot { float4 a0[3]; float4 a1[3]; };   // one token pair (24 VGPR)

__global__ __launch_bounds__(256)
void phm_fused(const float* __restrict__ x,
               const float* __restrict__ rule_d,
               const float* __restrict__ Wl_d,
               const float* __restrict__ Wr_d,
               const float* __restrict__ bias_d,
               const float* __restrict__ rule_u,
               const float* __restrict__ Wl_u,
               const float* __restrict__ Wr_u,
               const float* __restrict__ bias_u,
               float* __restrict__ out,
               int n_tokens)
{
    __shared__ __attribute__((aligned(16))) float sLd[768];    // W_left_d  [i][p]  i*192+p
    __shared__ __attribute__((aligned(16))) float sRu[768];    // W_right_u [i][q2] i*192+q2
    __shared__ __attribute__((aligned(16))) float sBu[768];    // bias_u
    __shared__ __attribute__((aligned(16))) float sLu[192];    // W_left_u  [i][q]  i*48+q
    __shared__ float sBd[192];                                 // bias_d
    __shared__ float sRd[192];                                 // W_right_d [i][q]  i*48+q
    __shared__ float sRuleD[64];                               // [i][a'][c] i*16+a'*4+c
    __shared__ float sRuleU[64];

    const int tid = threadIdx.x;
    for (int i = tid; i < 768; i += 256) sLd[i] = Wl_d[i];
    for (int i = tid; i < 768; i += 256) sRu[i] = Wr_u[i];
    for (int i = tid; i < 768; i += 256) sBu[i] = bias_u[i];
    if (tid < 192) {
        sLu[tid] = Wl_u[tid];
        sBd[tid] = bias_d[tid];
        sRd[tid] = Wr_d[tid];
    }
    if (tid < 64)       sRuleD[tid]     = rule_d[tid];
    else if (tid < 128) sRuleU[tid-64]  = rule_u[tid-64];

    const int lane = tid & 63;
    const int wave = tid >> 6;
    const int a    = lane >> 4;          // kron block 0..3 (also dest c)
    const int r    = lane & 15;          // slot within block
    const int off  = 192*a + 4*r;        // coalesced remap: +64u walks the block

    __syncthreads();   // the ONLY block barrier: weights staged

    const int wid     = blockIdx.x * 4 + wave;
    const int n_waves = gridDim.x * 4;
    const int n_pairs = n_tokens >> 1;

    auto issue = [&](Slot& S, int p) {
        const float* xp = x + (size_t)p * 1536 + off;
        #pragma unroll
        for (int u = 0; u < 3; ++u) {
            S.a0[u] = *(const float4*)(xp + 64*u);
            S.a1[u] = *(const float4*)(xp + 768 + 64*u);
        }
    };

    auto compute_store = [&](Slot& S, int p) {
        // ---- down dots: x[a*192 + 4r+64u + j] * Wl_d[i][4r+64u + j] ----
        float s0[4] = {0,0,0,0}, s1[4] = {0,0,0,0};
        #pragma unroll
        for (int u = 0; u < 3; ++u) {
            const float4 xa = S.a0[u];
            const float4 xb = S.a1[u];
            #pragma unroll
            for (int i = 0; i < 4; ++i) {
                const float4 lv = *(const float4*)&sLd[i*192 + 4*r + 64*u];
                s0[i] = fmaf(xa.x, lv.x, s0[i]);  s1[i] = fmaf(xb.x, lv.x, s1[i]);
                s0[i] = fmaf(xa.y, lv.y, s0[i]);  s1[i] = fmaf(xb.y, lv.y, s1[i]);
                s0[i] = fmaf(xa.z, lv.z, s0[i]);  s1[i] = fmaf(xb.z, lv.z, s1[i]);
                s0[i] = fmaf(xa.w, lv.w, s0[i]);  s1[i] = fmaf(xb.w, lv.w, s1[i]);
            }
        }

        // ---- 16-lane DPP reduce + permlane broadcast + rule contraction ----
        float tD0[4], tD1[4];
        #pragma unroll
        for (int i = 0; i < 4; ++i) {
            const float rk0 = sRuleD[i*16 +  0 + a];   // rule[i][0][a]
            const float rk1 = sRuleD[i*16 +  4 + a];
            const float rk2 = sRuleD[i*16 +  8 + a];
            const float rk3 = sRuleD[i*16 + 12 + a];
            float b0, b1, b2, b3;
            bcast4(reduce16(s0[i]), b0, b1, b2, b3);
            tD0[i] = fmaf(b0, rk0, fmaf(b1, rk1, fmaf(b2, rk2, b3 * rk3)));
            bcast4(reduce16(s1[i]), b0, b1, b2, b3);
            tD1[i] = fmaf(b0, rk0, fmaf(b1, rk1, fmaf(b2, rk2, b3 * rk3)));
        }

        // ---- z + gelu at o = a*48 + 3r + w ----
        float g0[3], g1[3];
        #pragma unroll
        for (int w = 0; w < 3; ++w) {
            float z0 = sBd[a*48 + 3*r + w], z1 = z0;
            #pragma unroll
            for (int i = 0; i < 4; ++i) {
                const float rd = sRd[i*48 + 3*r + w];
                z0 = fmaf(tD0[i], rd, z0);
                z1 = fmaf(tD1[i], rd, z1);
            }
            const float i0 = SQ2PI * fmaf(0.044715f*z0, z0*z0, z0);
            const float i1 = SQ2PI * fmaf(0.044715f*z1, z1*z1, z1);
            const float e0 = __expf(2.0f*i0);                // tanh(y)=1-2/(e^{2y}+1)
            const float e1 = __expf(2.0f*i1);
            g0[w] = 0.5f*z0*(1.0f + (1.0f - 2.0f/(e0 + 1.0f)));
            g1[w] = 0.5f*z1*(1.0f + (1.0f - 2.0f/(e1 + 1.0f)));
        }

        // ---- up dots + reduce + broadcast + rule contraction ----
        float tU0[4], tU1[4];
        #pragma unroll
        for (int i = 0; i < 4; ++i) {
            const float l0 = sLu[i*48 + 3*r + 0];
            const float l1 = sLu[i*48 + 3*r + 1];
            const float l2 = sLu[i*48 + 3*r + 2];
            const float rk0 = sRuleU[i*16 +  0 + a];
            const float rk1 = sRuleU[i*16 +  4 + a];
            const float rk2 = sRuleU[i*16 +  8 + a];
            const float rk3 = sRuleU[i*16 + 12 + a];
            float a0 = g0[0]*l0 + g0[1]*l1 + g0[2]*l2;
            float a1 = g1[0]*l0 + g1[1]*l1 + g1[2]*l2;
            float b0, b1, b2, b3;
            bcast4(reduce16(a0), b0, b1, b2, b3);
            tU0[i] = fmaf(b0, rk0, fmaf(b1, rk1, fmaf(b2, rk2, b3 * rk3)));
            bcast4(reduce16(a1), b0, b1, b2, b3);
            tU1[i] = fmaf(b0, rk0, fmaf(b1, rk1, fmaf(b2, rk2, b3 * rk3)));
        }

        // ---- outputs: coalesced nt stores ----
        float* op = out + (size_t)p * 1536 + off;
        #pragma unroll
        for (int u = 0; u < 3; ++u) {
            const float4 bv = *(const float4*)&sBu[off + 64*u];
            float4 ov0 = bv, ov1 = bv;
            #pragma unroll
            for (int i = 0; i < 4; ++i) {
                const float4 ru = *(const float4*)&sRu[i*192 + 4*r + 64*u];
                ov0.x = fmaf(tU0[i], ru.x, ov0.x);  ov1.x = fmaf(tU1[i], ru.x, ov1.x);
                ov0.y = fmaf(tU0[i], ru.y, ov0.y);  ov1.y = fmaf(tU1[i], ru.y, ov1.y);
                ov0.z = fmaf(tU0[i], ru.z, ov0.z);  ov1.z = fmaf(tU1[i], ru.z, ov1.z);
                ov0.w = fmaf(tU0[i], ru.w, ov0.w);  ov1.w = fmaf(tU1[i], ru.w, ov1.w);
            }
            nt_store4(op + 64*u,       ov0);
            nt_store4(op + 768 + 64*u, ov1);
        }
    };

    // ---- 3-slot ring, counted loop (simple CFG). Every wave handles
    //      pairs wid + k*n_waves, k = 0..cnt-1 (cnt = 4 for the bench shape).
    int cnt = 0;
    for (int p = wid; p < n_pairs; p += n_waves) ++cnt;

    Slot S0, S1, S2;
    if (cnt > 0)  issue(S0, wid);
    if (cnt > 1)  issue(S1, wid + n_waves);
    if (cnt > 2)  issue(S2, wid + 2*n_waves);

    int pr = wid;
    for (int k = 0; k + 2 < cnt; k += 3) {
        compute_store(S0, pr);
        if (k + 3 < cnt) issue(S0, pr + 3*n_waves);
        compute_store(S1, pr + n_waves);
        if (k + 4 < cnt) issue(S1, pr + 4*n_waves);
        compute_store(S2, pr + 2*n_waves);
        if (k + 5 < cnt) issue(S2, pr + 5*n_waves);
        pr += 3*n_waves;
    }
    // tail (cnt % 3 remaining, slots already loaded in ring order)
    const int rem = cnt % 3;
    const int done = cnt - rem;
    if (rem > 0) compute_store((done % 3 == 0) ? S0 : (done % 3 == 1) ? S1 : S2, pr);
    if (rem > 1) compute_store((done % 3 == 0) ? S1 : (done % 3 == 1) ? S2 : S0, pr + n_waves);
}

extern "C" void kernel_launch(void* const* d_in, const int* in_sizes, int n_in,
                              void* d_out, int out_size, void* d_ws, size_t ws_size,
                              hipStream_t stream) {
    const float* x      = (const float*)d_in[0];
    const float* rule_d = (const float*)d_in[1];
    const float* Wl_d   = (const float*)d_in[2];
    const float* Wr_d   = (const float*)d_in[3];
    const float* bias_d = (const float*)d_in[4];
    const float* rule_u = (const float*)d_in[5];
    const float* Wl_u   = (const float*)d_in[6];
    const float* Wr_u   = (const float*)d_in[7];
    const float* bias_u = (const float*)d_in[8];
    float* out          = (float*)d_out;

    const int n_tokens = in_sizes[0] / 768;   // 32768

    // 1024 blocks = 4096 waves; 16384 pairs -> exactly 4 pairs/wave (cnt=4).
    phm_fused<<<dim3(1024), dim3(256), 0, stream>>>(
        x, rule_d, Wl_d, Wr_d, bias_d, rule_u, Wl_u, Wr_u, bias_u, out, n_tokens);
}

// Round 10
// 196.643 us; speedup vs baseline: 1.0370x; 1.0370x over previous
//
#include <hip/hip_runtime.h>
#include <math.h>

// PHM adapter: down (768->192, n=4 rank-1 kron) -> gelu_new -> up (192->768).
// Round 14: MAX-TLP variant. r13 (3-slot ring) falsified the per-wave-MLP
// theory: VGPR 176, occupancy 9.7%, 77us (worse). Every 63-65us variant ran
// at exactly 4 waves/SIMD (VGPR 116-124) -- the one untested axis is MORE
// WAVES with LESS per-wave state. This version: ONE token per wave-iteration
// (A+B prefetch = 24 data regs), ALL weights/biases in LDS (r13 showed those
// reads are <=2-way bank aliasing = free per the LDS model), minimal live
// state -> target <=80 VGPR = 6-8 waves/SIMD = 1.5-2x the TLP of all prior
// attempts. Grid 2048 blocks (8/CU, LDS 8x12KB=98KB<160 not limiting).
// Prefetch loads are issued BEFORE the current token's stores so the vmcnt
// wait for next-token loads (in-order retirement) never waits on store
// completion. Keeps: coalesced remap p=a*192+4*(r+16u)+j, permlane
// broadcast, nt stores, no min-wave hint ((256,4) pins VGPR=64 and spills).

#define SQ2PI 0.79788456080286535588f

typedef float vfloat4 __attribute__((ext_vector_type(4)));
typedef unsigned int vuint2 __attribute__((ext_vector_type(2)));

template<int CTRL>
__device__ __forceinline__ float ror_add(float v) {
    // v + rotate_within_16(v, CTRL)  (DPP row_ror — VALU pipe, no DS traffic)
    int s = __builtin_amdgcn_update_dpp(0, __float_as_int(v), CTRL, 0xF, 0xF, true);
    return v + __int_as_float(s);
}
__device__ __forceinline__ float reduce16(float v) {
    v = ror_add<0x121>(v);   // row_ror:1
    v = ror_add<0x122>(v);   // row_ror:2
    v = ror_add<0x124>(v);   // row_ror:4
    v = ror_add<0x128>(v);   // row_ror:8
    return v;                // every lane: sum over its 16-lane row
}

// v_permlane16_swap_b32: exchanges odd 16-lane rows of d with even rows of s.
// v_permlane32_swap_b32: exchanges rows {2,3} of d with rows {0,1} of s.
__device__ __forceinline__ void swap16(float& d, float& s) {
    vuint2 t = __builtin_amdgcn_permlane16_swap(__float_as_uint(d), __float_as_uint(s), false, false);
    d = __uint_as_float(t.x);  s = __uint_as_float(t.y);
}
__device__ __forceinline__ void swap32(float& d, float& s) {
    vuint2 t = __builtin_amdgcn_permlane32_swap(__float_as_uint(d), __float_as_uint(s), false, false);
    d = __uint_as_float(t.x);  s = __uint_as_float(t.y);
}
// After reduce16, all lanes of row a hold H_a. Broadcast all four H's to
// every lane in 3 swap instructions (VALU pipe), no cndmask needed.
__device__ __forceinline__ void bcast4(float h, float& b0, float& b1, float& b2, float& b3) {
    float y1 = h, y2 = h;
    swap16(y1, y2);                     // y1 = H[a&2], y2 = H[(a&2)|1]
    b0 = y1; b2 = y1; swap32(b0, b2);   // b0 = H0, b2 = H2 (broadcast)
    b1 = y2; b3 = y2; swap32(b1, b3);   // b1 = H1, b3 = H3 (broadcast)
}

__device__ __forceinline__ void nt_store4(float* p, const float4& v) {
    vfloat4 nv;
    nv.x = v.x; nv.y = v.y; nv.z = v.z; nv.w = v.w;
    __builtin_nontemporal_store(nv, (vfloat4*)p);
}

__global__ __launch_bounds__(256)
void phm_fused(const float* __restrict__ x,
               const float* __restrict__ rule_d,
               const float* __restrict__ Wl_d,
               const float* __restrict__ Wr_d,
               const float* __restrict__ bias_d,
               const float* __restrict__ rule_u,
               const float* __restrict__ Wl_u,
               const float* __restrict__ Wr_u,
               const float* __restrict__ bias_u,
               float* __restrict__ out,
               int n_tokens)
{
    __shared__ __attribute__((aligned(16))) float sLd[768];    // W_left_d  [i][p]  i*192+p
    __shared__ __attribute__((aligned(16))) float sRu[768];    // W_right_u [i][q2] i*192+q2
    __shared__ __attribute__((aligned(16))) float sBu[768];    // bias_u
    __shared__ __attribute__((aligned(16))) float sLu[192];    // W_left_u  [i][q]  i*48+q
    __shared__ float sBd[192];                                 // bias_d
    __shared__ float sRd[192];                                 // W_right_d [i][q]  i*48+q
    __shared__ float sRuleD[64];                               // [i][a'][c] i*16+a'*4+c
    __shared__ float sRuleU[64];

    const int tid = threadIdx.x;
    for (int i = tid; i < 768; i += 256) sLd[i] = Wl_d[i];
    for (int i = tid; i < 768; i += 256) sRu[i] = Wr_u[i];
    for (int i = tid; i < 768; i += 256) sBu[i] = bias_u[i];
    if (tid < 192) {
        sLu[tid] = Wl_u[tid];
        sBd[tid] = bias_d[tid];
        sRd[tid] = Wr_d[tid];
    }
    if (tid < 64)       sRuleD[tid]     = rule_d[tid];
    else if (tid < 128) sRuleU[tid-64]  = rule_u[tid-64];

    const int lane = tid & 63;
    const int wave = tid >> 6;
    const int a    = lane >> 4;          // kron block 0..3 (also dest c)
    const int r    = lane & 15;          // slot within block
    const int off  = 192*a + 4*r;        // coalesced remap: +64u walks the block

    __syncthreads();   // the ONLY block barrier: weights staged

    const int wid     = blockIdx.x * 4 + wave;
    const int n_waves = gridDim.x * 4;   // 8192 for the bench shape

    // ---- prologue: load first token ----
    float4 A0, A1, A2;
    if (wid < n_tokens) {
        const float* xp = x + (size_t)wid * 768 + off;
        A0 = *(const float4*)(xp);
        A1 = *(const float4*)(xp + 64);
        A2 = *(const float4*)(xp + 128);
    }

    for (int t = wid; t < n_tokens; t += n_waves) {
        // ---- prefetch next token FIRST (before this token's stores) ----
        const int tn = t + n_waves;
        const float* np = x + (size_t)(tn < n_tokens ? tn : t) * 768 + off;
        float4 B0 = *(const float4*)(np);
        float4 B1 = *(const float4*)(np + 64);
        float4 B2 = *(const float4*)(np + 128);

        // ---- down dots: x[a*192 + 4r+64u + j] * Wl_d[i][4r+64u + j] ----
        float s[4] = {0,0,0,0};
        #pragma unroll
        for (int i = 0; i < 4; ++i) {
            const float4 l0 = *(const float4*)&sLd[i*192 + 4*r];
            const float4 l1 = *(const float4*)&sLd[i*192 + 4*r + 64];
            const float4 l2 = *(const float4*)&sLd[i*192 + 4*r + 128];
            s[i] = fmaf(A0.x, l0.x, s[i]);  s[i] = fmaf(A0.y, l0.y, s[i]);
            s[i] = fmaf(A0.z, l0.z, s[i]);  s[i] = fmaf(A0.w, l0.w, s[i]);
            s[i] = fmaf(A1.x, l1.x, s[i]);  s[i] = fmaf(A1.y, l1.y, s[i]);
            s[i] = fmaf(A1.z, l1.z, s[i]);  s[i] = fmaf(A1.w, l1.w, s[i]);
            s[i] = fmaf(A2.x, l2.x, s[i]);  s[i] = fmaf(A2.y, l2.y, s[i]);
            s[i] = fmaf(A2.z, l2.z, s[i]);  s[i] = fmaf(A2.w, l2.w, s[i]);
        }

        // ---- 16-lane DPP reduce + permlane broadcast + rule contraction ----
        float tD[4];
        #pragma unroll
        for (int i = 0; i < 4; ++i) {
            const float rk0 = sRuleD[i*16 +  0 + a];   // rule[i][0][a]
            const float rk1 = sRuleD[i*16 +  4 + a];
            const float rk2 = sRuleD[i*16 +  8 + a];
            const float rk3 = sRuleD[i*16 + 12 + a];
            float b0, b1, b2, b3;
            bcast4(reduce16(s[i]), b0, b1, b2, b3);
            tD[i] = fmaf(b0, rk0, fmaf(b1, rk1, fmaf(b2, rk2, b3 * rk3)));
        }

        // ---- z + gelu at o = a*48 + 3r + w ----
        float g[3];
        #pragma unroll
        for (int w = 0; w < 3; ++w) {
            float z = sBd[a*48 + 3*r + w];
            #pragma unroll
            for (int i = 0; i < 4; ++i)
                z = fmaf(tD[i], sRd[i*48 + 3*r + w], z);
            const float iv = SQ2PI * fmaf(0.044715f*z, z*z, z);
            const float e  = __expf(2.0f*iv);               // tanh(y)=1-2/(e^{2y}+1)
            g[w] = 0.5f*z*(1.0f + (1.0f - 2.0f/(e + 1.0f)));
        }

        // ---- up dots + reduce + broadcast + rule contraction ----
        float tU[4];
        #pragma unroll
        for (int i = 0; i < 4; ++i) {
            const float l0 = sLu[i*48 + 3*r + 0];
            const float l1 = sLu[i*48 + 3*r + 1];
            const float l2 = sLu[i*48 + 3*r + 2];
            const float rk0 = sRuleU[i*16 +  0 + a];
            const float rk1 = sRuleU[i*16 +  4 + a];
            const float rk2 = sRuleU[i*16 +  8 + a];
            const float rk3 = sRuleU[i*16 + 12 + a];
            float a0 = g[0]*l0 + g[1]*l1 + g[2]*l2;
            float b0, b1, b2, b3;
            bcast4(reduce16(a0), b0, b1, b2, b3);
            tU[i] = fmaf(b0, rk0, fmaf(b1, rk1, fmaf(b2, rk2, b3 * rk3)));
        }

        // ---- outputs: coalesced nt stores ----
        float* op = out + (size_t)t * 768 + off;
        #pragma unroll
        for (int u = 0; u < 3; ++u) {
            float4 ov = *(const float4*)&sBu[off + 64*u];
            #pragma unroll
            for (int i = 0; i < 4; ++i) {
                const float4 ru = *(const float4*)&sRu[i*192 + 4*r + 64*u];
                ov.x = fmaf(tU[i], ru.x, ov.x);
                ov.y = fmaf(tU[i], ru.y, ov.y);
                ov.z = fmaf(tU[i], ru.z, ov.z);
                ov.w = fmaf(tU[i], ru.w, ov.w);
            }
            nt_store4(op + 64*u, ov);
        }

        // ---- rotate prefetch into current ----
        A0 = B0; A1 = B1; A2 = B2;
    }
}

extern "C" void kernel_launch(void* const* d_in, const int* in_sizes, int n_in,
                              void* d_out, int out_size, void* d_ws, size_t ws_size,
                              hipStream_t stream) {
    const float* x      = (const float*)d_in[0];
    const float* rule_d = (const float*)d_in[1];
    const float* Wl_d   = (const float*)d_in[2];
    const float* Wr_d   = (const float*)d_in[3];
    const float* bias_d = (const float*)d_in[4];
    const float* rule_u = (const float*)d_in[5];
    const float* Wl_u   = (const float*)d_in[6];
    const float* Wr_u   = (const float*)d_in[7];
    const float* bias_u = (const float*)d_in[8];
    float* out          = (float*)d_out;

    const int n_tokens = in_sizes[0] / 768;   // 32768

    // 2048 blocks = 8192 waves (8 blocks/CU); 32768 tokens -> 4 tokens/wave.
    const int blocks = (n_tokens + 15) / 16;
    phm_fused<<<dim3(blocks), dim3(256), 0, stream>>>(
        x, rule_d, Wl_d, Wr_d, bias_d, rule_u, Wl_u, Wr_u, bias_u, out, n_tokens);
}